// Round 2
// baseline (11874.891 us; speedup 1.0000x reference)
//
#include <hip/hip_runtime.h>
#include <hip/hip_bf16.h>
#include <math.h>

#define B_ 2
#define S_ 2048
#define D_ 1024
#define H_ 16
#define HD_ 64
#define L_ 6
#define NTOK (B_*S_)

typedef unsigned short ushort_t;
typedef unsigned int uint_t;

typedef __attribute__((ext_vector_type(8))) short bf16x8;
typedef __attribute__((ext_vector_type(4))) float f32x4;

__device__ __forceinline__ float bf2f(ushort_t u) {
    return __uint_as_float(((uint_t)u) << 16);
}
__device__ __forceinline__ ushort_t f2bf(float f) {
    uint_t x = __float_as_uint(f);
    uint_t r = (x + 0x7FFFu + ((x >> 16) & 1u)) >> 16;
    return (ushort_t)r;
}
__device__ __forceinline__ float bflo(uint_t u){ return __uint_as_float(u << 16); }
__device__ __forceinline__ float bfhi(uint_t u){ return __uint_as_float(u & 0xFFFF0000u); }

// ---------------- fp32 -> bf16 conversion (weights) ----------------
__global__ __launch_bounds__(256) void cvt_kernel(const float* __restrict__ in,
                                                  ushort_t* __restrict__ out) {
    int i = (blockIdx.x * 256 + threadIdx.x) * 4;
    float4 v = *(const float4*)(in + i);
    ushort_t o[4] = { f2bf(v.x), f2bf(v.y), f2bf(v.z), f2bf(v.w) };
    *(uint2*)(out + i) = *(const uint2*)o;
}

// ---------------- embedding + positional encoding ----------------
__global__ void embed_kernel(const int* __restrict__ x, const float* __restrict__ emb,
                             float* __restrict__ h, ushort_t* __restrict__ hb) {
    int row = blockIdx.x;            // 0..NTOK-1
    int s = row % S_;
    int tok = x[row];
    const float* erow = emb + (size_t)tok * D_;
    float* hrow = h + (size_t)row * D_;
    ushort_t* hbrow = hb + (size_t)row * D_;
    const float kExp = -2.0f * 13.287712379549449f / (float)D_;  // -2*log2(10000)/D
    for (int c = threadIdx.x; c < D_; c += blockDim.x) {
        float factor = exp2f(kExp * (float)c);
        float ang = (float)s * factor;
        float pe = (c & 1) ? cosf(ang) : sinf(ang);
        float v = erow[c] * 32.0f + pe;
        hrow[c] = v;
        hbrow[c] = f2bf(v);
    }
}

// ---------------- generic bf16 MFMA GEMM: C = A[MxK] @ B[KxN] (+bias)(relu) ----------------
#define GEMM_OUT_BF16 1
#define GEMM_RELU 2

__global__ __launch_bounds__(256) void gemm_kernel(
    const ushort_t* __restrict__ A, const ushort_t* __restrict__ Bm,
    const float* __restrict__ bias, void* __restrict__ out,
    int M, int N, int K, int flags)
{
    __shared__ __align__(16) ushort_t sA[64*40];   // [row][k], padded stride 40
    __shared__ __align__(16) ushort_t sBt[64*40];  // [col][k], padded stride 40

    int t = threadIdx.x;
    int lane = t & 63, w = t >> 6;
    int ln15 = lane & 15, q = lane >> 4;
    int n0 = blockIdx.x * 64, m0 = blockIdx.y * 64;

    f32x4 acc[4];
#pragma unroll
    for (int i = 0; i < 4; i++) acc[i] = (f32x4){0.f, 0.f, 0.f, 0.f};

    int arow = t >> 2, ac = (t & 3) * 8;   // A tile: 64 rows x 32 k
    int krow = t >> 3, nc = (t & 7) * 8;   // B tile: 32 k   x 64 cols
    int ml = w * 16 + ln15;

    for (int k0 = 0; k0 < K; k0 += 32) {
        uint4 av = *(const uint4*)(A + (size_t)(m0 + arow) * K + k0 + ac);
        uint4 bv = *(const uint4*)(Bm + (size_t)(k0 + krow) * N + n0 + nc);
        __syncthreads();   // protect previous iteration's fragment reads
        *(uint4*)(&sA[arow * 40 + ac]) = av;
        const ushort_t* bvp = (const ushort_t*)&bv;
#pragma unroll
        for (int j = 0; j < 8; j++) sBt[(nc + j) * 40 + krow] = bvp[j];
        __syncthreads();
        bf16x8 af = *(const bf16x8*)(&sA[ml * 40 + q * 8]);
#pragma unroll
        for (int cb = 0; cb < 4; cb++) {
            bf16x8 bf = *(const bf16x8*)(&sBt[(cb * 16 + ln15) * 40 + q * 8]);
            acc[cb] = __builtin_amdgcn_mfma_f32_16x16x32_bf16(af, bf, acc[cb], 0, 0, 0);
        }
    }

#pragma unroll
    for (int cb = 0; cb < 4; cb++) {
#pragma unroll
        for (int r = 0; r < 4; r++) {
            int row = m0 + w * 16 + q * 4 + r;
            int col = n0 + cb * 16 + ln15;
            float v = acc[cb][r];
            if (bias) v += bias[col];
            if (flags & GEMM_RELU) v = fmaxf(v, 0.f);
            if (flags & GEMM_OUT_BF16)
                ((ushort_t*)out)[(size_t)row * N + col] = f2bf(v);
            else
                ((float*)out)[(size_t)row * N + col] = v;
        }
    }
}

// ---------------- flash attention (thread-per-query-row) ----------------
__global__ __launch_bounds__(128) void attn_kernel(
    const ushort_t* __restrict__ Q, const ushort_t* __restrict__ Km,
    const ushort_t* __restrict__ Vm, ushort_t* __restrict__ O)
{
    __shared__ float sK[64 * 64];
    __shared__ float sV[64 * 64];
    int t = threadIdx.x;
    int b = blockIdx.z, hh = blockIdx.y;
    int qrow = blockIdx.x * 128 + t;
    const size_t qoff = ((size_t)b * S_ + qrow) * D_ + hh * HD_;

    float4 q4[16];
    {
        const uint4* qp = (const uint4*)(Q + qoff);
#pragma unroll
        for (int i = 0; i < 8; i++) {
            uint4 u = qp[i];
            q4[2*i+0] = make_float4(bflo(u.x), bfhi(u.x), bflo(u.y), bfhi(u.y));
            q4[2*i+1] = make_float4(bflo(u.z), bfhi(u.z), bflo(u.w), bfhi(u.w));
        }
    }
    float4 o4[16];
#pragma unroll
    for (int i = 0; i < 16; i++) o4[i] = make_float4(0.f, 0.f, 0.f, 0.f);
    float m = -1e30f, lsum = 0.f;

    int key = t >> 1;          // 0..63
    int dh = (t & 1) * 32;     // 0 or 32
    for (int k0 = 0; k0 < S_; k0 += 64) {
        const uint4* kp = (const uint4*)(Km + ((size_t)b * S_ + k0 + key) * D_ + hh * HD_ + dh);
        const uint4* vp = (const uint4*)(Vm + ((size_t)b * S_ + k0 + key) * D_ + hh * HD_ + dh);
        uint4 kv[4], vv[4];
#pragma unroll
        for (int i = 0; i < 4; i++) { kv[i] = kp[i]; vv[i] = vp[i]; }
        __syncthreads();
        float4* dk = (float4*)&sK[key * 64 + dh];
        float4* dv = (float4*)&sV[key * 64 + dh];
#pragma unroll
        for (int i = 0; i < 4; i++) {
            dk[2*i+0] = make_float4(bflo(kv[i].x), bfhi(kv[i].x), bflo(kv[i].y), bfhi(kv[i].y));
            dk[2*i+1] = make_float4(bflo(kv[i].z), bfhi(kv[i].z), bflo(kv[i].w), bfhi(kv[i].w));
            dv[2*i+0] = make_float4(bflo(vv[i].x), bfhi(vv[i].x), bflo(vv[i].y), bfhi(vv[i].y));
            dv[2*i+1] = make_float4(bflo(vv[i].z), bfhi(vv[i].z), bflo(vv[i].w), bfhi(vv[i].w));
        }
        __syncthreads();

        for (int kk = 0; kk < 64; kk++) {
            const float4* kr = (const float4*)&sK[kk * 64];
            float s = 0.f;
#pragma unroll
            for (int dvi = 0; dvi < 16; dvi++) {
                float4 kf = kr[dvi];
                s += q4[dvi].x * kf.x + q4[dvi].y * kf.y + q4[dvi].z * kf.z + q4[dvi].w * kf.w;
            }
            s *= 0.125f;   // 1/sqrt(64)
            if (s > m) {
                float corr = __expf(m - s);
                lsum *= corr;
#pragma unroll
                for (int dvi = 0; dvi < 16; dvi++) {
                    o4[dvi].x *= corr; o4[dvi].y *= corr; o4[dvi].z *= corr; o4[dvi].w *= corr;
                }
                m = s;
            }
            float p = __expf(s - m);
            lsum += p;
            const float4* vr = (const float4*)&sV[kk * 64];
#pragma unroll
            for (int dvi = 0; dvi < 16; dvi++) {
                float4 vf = vr[dvi];
                o4[dvi].x += p * vf.x; o4[dvi].y += p * vf.y;
                o4[dvi].z += p * vf.z; o4[dvi].w += p * vf.w;
            }
        }
    }
    float inv = 1.0f / lsum;
    ushort_t* op = O + qoff;
#pragma unroll
    for (int dvi = 0; dvi < 16; dvi++) {
        op[dvi*4+0] = f2bf(o4[dvi].x * inv);
        op[dvi*4+1] = f2bf(o4[dvi].y * inv);
        op[dvi*4+2] = f2bf(o4[dvi].z * inv);
        op[dvi*4+3] = f2bf(o4[dvi].w * inv);
    }
}

// ---------------- fused residual-add + LayerNorm (fp32 + bf16 outputs) ----------------
__global__ __launch_bounds__(256) void ln_add_kernel(
    const float* __restrict__ a, const float* __restrict__ bres,
    const float* __restrict__ g, const float* __restrict__ be,
    float* __restrict__ of, ushort_t* __restrict__ ob)
{
    int row = blockIdx.x;
    int t = threadIdx.x;
    const float* ar = a + (size_t)row * D_;
    const float* br = bres + (size_t)row * D_;
    float x[4];
    float s = 0.f, sq = 0.f;
#pragma unroll
    for (int i = 0; i < 4; i++) {
        int c = t + i * 256;
        float v = ar[c] + br[c];
        x[i] = v; s += v; sq += v * v;
    }
#pragma unroll
    for (int off = 32; off; off >>= 1) {
        s += __shfl_xor(s, off);
        sq += __shfl_xor(sq, off);
    }
    __shared__ float rs[4], rq[4];
    int w = t >> 6;
    if ((t & 63) == 0) { rs[w] = s; rq[w] = sq; }
    __syncthreads();
    s = rs[0] + rs[1] + rs[2] + rs[3];
    sq = rq[0] + rq[1] + rq[2] + rq[3];
    float mu = s * (1.0f / D_);
    float var = sq * (1.0f / D_) - mu * mu;
    float rstd = rsqrtf(var + 1e-5f);
#pragma unroll
    for (int i = 0; i < 4; i++) {
        int c = t + i * 256;
        float y = (x[i] - mu) * rstd * g[c] + be[c];
        of[(size_t)row * D_ + c] = y;
        ob[(size_t)row * D_ + c] = f2bf(y);
    }
}

extern "C" void kernel_launch(void* const* d_in, const int* in_sizes, int n_in,
                              void* d_out, int out_size, void* d_ws, size_t ws_size,
                              hipStream_t stream) {
    const int*   x    = (const int*)d_in[0];
    const float* emb  = (const float*)d_in[1];
    const float* Wq   = (const float*)d_in[2];
    const float* Wk   = (const float*)d_in[3];
    const float* Wv   = (const float*)d_in[4];
    const float* Wo   = (const float*)d_in[5];
    const float* bo   = (const float*)d_in[6];
    const float* ln1g = (const float*)d_in[7];
    const float* ln1b = (const float*)d_in[8];
    const float* W1   = (const float*)d_in[9];
    const float* b1   = (const float*)d_in[10];
    const float* W2   = (const float*)d_in[11];
    const float* b2   = (const float*)d_in[12];
    const float* ln2g = (const float*)d_in[13];
    const float* ln2b = (const float*)d_in[14];

    char* ws = (char*)d_ws;
    float*    h   = (float*)(ws + 0);             // 16 MB fp32 residual
    ushort_t* hb  = (ushort_t*)(ws + 16777216);   // 8 MB bf16 h
    float*    t0  = (float*)(ws + 25165824);      // 16 MB fp32 gemm out
    float*    n1  = (float*)(ws + 41943040);      // 16 MB fp32 n1
    ushort_t* n1b = (ushort_t*)(ws + 58720256);   // 8 MB bf16 n1
    ushort_t* qb  = (ushort_t*)(ws + 67108864);   // 8 MB
    ushort_t* kb  = (ushort_t*)(ws + 75497472);   // 8 MB
    ushort_t* vb  = (ushort_t*)(ws + 83886080);   // 8 MB
    ushort_t* ab  = (ushort_t*)(ws + 92274688);   // 8 MB
    ushort_t* ff1 = (ushort_t*)(ws + 67108864);   // 32 MB, overlaps dead qkv/ab
    ushort_t* wqb = (ushort_t*)(ws + 100663296);  // 2 MB
    ushort_t* wkb = (ushort_t*)(ws + 102760448);  // 2 MB
    ushort_t* wvb = (ushort_t*)(ws + 104857600);  // 2 MB
    ushort_t* wob = (ushort_t*)(ws + 106954752);  // 2 MB
    ushort_t* w1b = (ushort_t*)(ws + 109051904);  // 8 MB
    ushort_t* w2b = (ushort_t*)(ws + 117440512);  // 8 MB  (total 120 MB)

    embed_kernel<<<NTOK, 256, 0, stream>>>(x, emb, h, hb);

    for (int l = 0; l < L_; l++) {
        const float* Wq_l = Wq + (size_t)l * D_ * D_;
        const float* Wk_l = Wk + (size_t)l * D_ * D_;
        const float* Wv_l = Wv + (size_t)l * D_ * D_;
        const float* Wo_l = Wo + (size_t)l * D_ * D_;
        const float* bo_l = bo + (size_t)l * D_;
        const float* W1_l = W1 + (size_t)l * D_ * 4 * D_;
        const float* b1_l = b1 + (size_t)l * 4 * D_;
        const float* W2_l = W2 + (size_t)l * 4 * D_ * D_;
        const float* b2_l = b2 + (size_t)l * D_;

        cvt_kernel<<<D_*D_/1024, 256, 0, stream>>>(Wq_l, wqb);
        cvt_kernel<<<D_*D_/1024, 256, 0, stream>>>(Wk_l, wkb);
        cvt_kernel<<<D_*D_/1024, 256, 0, stream>>>(Wv_l, wvb);
        cvt_kernel<<<D_*D_/1024, 256, 0, stream>>>(Wo_l, wob);
        cvt_kernel<<<4*D_*D_/1024, 256, 0, stream>>>(W1_l, w1b);
        cvt_kernel<<<4*D_*D_/1024, 256, 0, stream>>>(W2_l, w2b);

        dim3 gProj(D_ / 64, NTOK / 64);
        gemm_kernel<<<gProj, 256, 0, stream>>>(hb, wqb, nullptr, qb, NTOK, D_, D_, GEMM_OUT_BF16);
        gemm_kernel<<<gProj, 256, 0, stream>>>(hb, wkb, nullptr, kb, NTOK, D_, D_, GEMM_OUT_BF16);
        gemm_kernel<<<gProj, 256, 0, stream>>>(hb, wvb, nullptr, vb, NTOK, D_, D_, GEMM_OUT_BF16);

        attn_kernel<<<dim3(S_ / 128, H_, B_), 128, 0, stream>>>(qb, kb, vb, ab);

        gemm_kernel<<<gProj, 256, 0, stream>>>(ab, wob, bo_l, t0, NTOK, D_, D_, 0);
        ln_add_kernel<<<NTOK, 256, 0, stream>>>(t0, h, ln1g + l * D_, ln1b + l * D_, n1, n1b);

        dim3 gW1(4 * D_ / 64, NTOK / 64);
        gemm_kernel<<<gW1, 256, 0, stream>>>(n1b, w1b, b1_l, ff1, NTOK, 4 * D_, D_, GEMM_OUT_BF16 | GEMM_RELU);
        dim3 gW2(D_ / 64, NTOK / 64);
        gemm_kernel<<<gW2, 256, 0, stream>>>(ff1, w2b, b2_l, t0, NTOK, D_, 4 * D_, 0);

        float* of = (l == L_ - 1) ? (float*)d_out : h;
        ln_add_kernel<<<NTOK, 256, 0, stream>>>(t0, n1, ln2g + l * D_, ln2b + l * D_, of, hb);
    }
}

// Round 3
// 4477.396 us; speedup vs baseline: 2.6522x; 2.6522x over previous
//
#include <hip/hip_runtime.h>
#include <hip/hip_bf16.h>
#include <math.h>

#define B_ 2
#define S_ 2048
#define D_ 1024
#define H_ 16
#define HD_ 64
#define L_ 6
#define NTOK (B_*S_)

typedef unsigned short ushort_t;
typedef unsigned int uint_t;

typedef __attribute__((ext_vector_type(8))) short bf16x8;
typedef __attribute__((ext_vector_type(4))) float f32x4;

__device__ __forceinline__ float bf2f(ushort_t u) {
    return __uint_as_float(((uint_t)u) << 16);
}
__device__ __forceinline__ ushort_t f2bf(float f) {
    uint_t x = __float_as_uint(f);
    uint_t r = (x + 0x7FFFu + ((x >> 16) & 1u)) >> 16;
    return (ushort_t)r;
}

// ---------------- fp32 -> bf16 conversion (weights) ----------------
__global__ __launch_bounds__(256) void cvt_kernel(const float* __restrict__ in,
                                                  ushort_t* __restrict__ out) {
    int i = (blockIdx.x * 256 + threadIdx.x) * 4;
    float4 v = *(const float4*)(in + i);
    ushort_t o[4] = { f2bf(v.x), f2bf(v.y), f2bf(v.z), f2bf(v.w) };
    *(uint2*)(out + i) = *(const uint2*)o;
}

// ---------------- embedding + positional encoding ----------------
__global__ void embed_kernel(const int* __restrict__ x, const float* __restrict__ emb,
                             float* __restrict__ h, ushort_t* __restrict__ hb) {
    int row = blockIdx.x;            // 0..NTOK-1
    int s = row % S_;
    int tok = x[row];
    const float* erow = emb + (size_t)tok * D_;
    float* hrow = h + (size_t)row * D_;
    ushort_t* hbrow = hb + (size_t)row * D_;
    const float kExp = -2.0f * 13.287712379549449f / (float)D_;  // -2*log2(10000)/D
    for (int c = threadIdx.x; c < D_; c += blockDim.x) {
        float factor = exp2f(kExp * (float)c);
        float ang = (float)s * factor;
        float pe = (c & 1) ? cosf(ang) : sinf(ang);
        float v = erow[c] * 32.0f + pe;
        hrow[c] = v;
        hbrow[c] = f2bf(v);
    }
}

// ---------------- generic bf16 MFMA GEMM: C = A[MxK] @ B[KxN] (+bias)(relu) ----------------
#define GEMM_OUT_BF16 1
#define GEMM_RELU 2

__global__ __launch_bounds__(256) void gemm_kernel(
    const ushort_t* __restrict__ A, const ushort_t* __restrict__ Bm,
    const float* __restrict__ bias, void* __restrict__ out,
    int M, int N, int K, int flags)
{
    __shared__ __align__(16) ushort_t sA[64*40];   // [row][k], padded stride 40
    __shared__ __align__(16) ushort_t sBt[64*40];  // [col][k], padded stride 40

    int t = threadIdx.x;
    int lane = t & 63, w = t >> 6;
    int ln15 = lane & 15, q = lane >> 4;
    int n0 = blockIdx.x * 64, m0 = blockIdx.y * 64;

    f32x4 acc[4];
#pragma unroll
    for (int i = 0; i < 4; i++) acc[i] = (f32x4){0.f, 0.f, 0.f, 0.f};

    int arow = t >> 2, ac = (t & 3) * 8;   // A tile: 64 rows x 32 k
    int krow = t >> 3, nc = (t & 7) * 8;   // B tile: 32 k   x 64 cols
    int ml = w * 16 + ln15;

    for (int k0 = 0; k0 < K; k0 += 32) {
        uint4 av = *(const uint4*)(A + (size_t)(m0 + arow) * K + k0 + ac);
        uint4 bv = *(const uint4*)(Bm + (size_t)(k0 + krow) * N + n0 + nc);
        __syncthreads();   // protect previous iteration's fragment reads
        *(uint4*)(&sA[arow * 40 + ac]) = av;
        const ushort_t* bvp = (const ushort_t*)&bv;
#pragma unroll
        for (int j = 0; j < 8; j++) sBt[(nc + j) * 40 + krow] = bvp[j];
        __syncthreads();
        bf16x8 af = *(const bf16x8*)(&sA[ml * 40 + q * 8]);
#pragma unroll
        for (int cb = 0; cb < 4; cb++) {
            bf16x8 bf = *(const bf16x8*)(&sBt[(cb * 16 + ln15) * 40 + q * 8]);
            acc[cb] = __builtin_amdgcn_mfma_f32_16x16x32_bf16(af, bf, acc[cb], 0, 0, 0);
        }
    }

#pragma unroll
    for (int cb = 0; cb < 4; cb++) {
#pragma unroll
        for (int r = 0; r < 4; r++) {
            int row = m0 + w * 16 + q * 4 + r;
            int col = n0 + cb * 16 + ln15;
            float v = acc[cb][r];
            if (bias) v += bias[col];
            if (flags & GEMM_RELU) v = fmaxf(v, 0.f);
            if (flags & GEMM_OUT_BF16)
                ((ushort_t*)out)[(size_t)row * N + col] = f2bf(v);
            else
                ((float*)out)[(size_t)row * N + col] = v;
        }
    }
}

// ---------------- MFMA flash attention ----------------
// Block: 256 threads (4 waves). Each block: 64 q-rows (16 per wave) of one (b,h).
// K-tiles of 64 keys. QK^T and PV both via mfma_f32_16x16x32_bf16.
#define SKP 72   // LDS row stride (elems) for sK / sVt / sP; 144 B keeps b128 16B-aligned

__global__ __launch_bounds__(256) void attn_kernel(
    const ushort_t* __restrict__ Q, const ushort_t* __restrict__ Km,
    const ushort_t* __restrict__ Vm, ushort_t* __restrict__ O)
{
    __shared__ __align__(16) ushort_t sK[64 * SKP];    // [key][hd]
    __shared__ __align__(16) ushort_t sVt[64 * SKP];   // [hd][key]
    __shared__ __align__(16) ushort_t sP[4][16 * SKP]; // per-wave P [qrow][key]

    int t = threadIdx.x;
    int w = t >> 6, lane = t & 63;
    int ln15 = lane & 15, q = lane >> 4;
    int b = blockIdx.z, hh = blockIdx.y;
    int q0 = blockIdx.x * 64;

    const size_t base = (size_t)b * S_ * D_ + hh * HD_;

    // Q fragments (A layout): row m = ln15 (of this wave's 16 rows), k = q*8+j (+32c)
    bf16x8 aq[2];
    {
        const ushort_t* qrow = Q + base + (size_t)(q0 + w * 16 + ln15) * D_;
        aq[0] = *(const bf16x8*)(qrow + q * 8);
        aq[1] = *(const bf16x8*)(qrow + 32 + q * 8);
    }

    f32x4 accO[4];
#pragma unroll
    for (int i = 0; i < 4; i++) accO[i] = (f32x4){0.f, 0.f, 0.f, 0.f};
    float mrow[4] = {-1e30f, -1e30f, -1e30f, -1e30f};
    float lrow[4] = {0.f, 0.f, 0.f, 0.f};

    // staging index precompute
    int kkey = t >> 3, khd = (t & 7) * 8;       // K: 8 lanes cover one key row (128B coalesced)
    int vkey = t & 63, vhd = (t >> 6) * 8;      // V: lane==key -> conflict-free transpose stores

    for (int k0 = 0; k0 < S_; k0 += 64) {
        uint4 kv0 = *(const uint4*)(Km + base + (size_t)(k0 + kkey) * D_ + khd);
        uint4 kv1 = *(const uint4*)(Km + base + (size_t)(k0 + 32 + kkey) * D_ + khd);
        uint4 vv0 = *(const uint4*)(Vm + base + (size_t)(k0 + vkey) * D_ + vhd);
        uint4 vv1 = *(const uint4*)(Vm + base + (size_t)(k0 + vkey) * D_ + 32 + vhd);
        __syncthreads();   // all waves done reading previous tile
        *(uint4*)(&sK[kkey * SKP + khd]) = kv0;
        *(uint4*)(&sK[(kkey + 32) * SKP + khd]) = kv1;
        const ushort_t* vp0 = (const ushort_t*)&vv0;
        const ushort_t* vp1 = (const ushort_t*)&vv1;
#pragma unroll
        for (int j = 0; j < 8; j++) {
            sVt[(vhd + j) * SKP + vkey] = vp0[j];
            sVt[(vhd + 32 + j) * SKP + vkey] = vp1[j];
        }
        __syncthreads();

        // scores: S[16 q x 64 keys] per wave, C layout (row=4q+r, col=key nb*16+ln15)
        f32x4 sc[4];
#pragma unroll
        for (int nb = 0; nb < 4; nb++) {
            bf16x8 bk0 = *(const bf16x8*)(&sK[(nb * 16 + ln15) * SKP + q * 8]);
            bf16x8 bk1 = *(const bf16x8*)(&sK[(nb * 16 + ln15) * SKP + 32 + q * 8]);
            f32x4 z = (f32x4){0.f, 0.f, 0.f, 0.f};
            z = __builtin_amdgcn_mfma_f32_16x16x32_bf16(aq[0], bk0, z, 0, 0, 0);
            z = __builtin_amdgcn_mfma_f32_16x16x32_bf16(aq[1], bk1, z, 0, 0, 0);
            sc[nb] = z;
        }

        // online softmax update (per q-row r; lane holds cols ln15+16nb)
        float p[4][4];
#pragma unroll
        for (int r = 0; r < 4; r++) {
            float s0 = sc[0][r] * 0.125f, s1 = sc[1][r] * 0.125f;
            float s2 = sc[2][r] * 0.125f, s3 = sc[3][r] * 0.125f;
            float pm = fmaxf(fmaxf(s0, s1), fmaxf(s2, s3));
#pragma unroll
            for (int off = 1; off < 16; off <<= 1)
                pm = fmaxf(pm, __shfl_xor(pm, off));
            float mnew = fmaxf(mrow[r], pm);
            float alpha = __expf(mrow[r] - mnew);
            mrow[r] = mnew;
            float p0 = __expf(s0 - mnew), p1 = __expf(s1 - mnew);
            float p2 = __expf(s2 - mnew), p3 = __expf(s3 - mnew);
            p[0][r] = p0; p[1][r] = p1; p[2][r] = p2; p[3][r] = p3;
            lrow[r] = lrow[r] * alpha + (p0 + p1 + p2 + p3);
            accO[0][r] *= alpha; accO[1][r] *= alpha;
            accO[2][r] *= alpha; accO[3][r] *= alpha;
        }

        // P -> LDS (C layout positions), reload in A layout. Per-wave buffer: no barrier.
#pragma unroll
        for (int nb = 0; nb < 4; nb++)
#pragma unroll
            for (int r = 0; r < 4; r++)
                sP[w][(q * 4 + r) * SKP + nb * 16 + ln15] = f2bf(p[nb][r]);

        // PV: O[16 q x 64 hd] += P[16x64] @ V[64 keys x 64 hd]
#pragma unroll
        for (int c = 0; c < 2; c++) {
            bf16x8 ap = *(const bf16x8*)(&sP[w][ln15 * SKP + c * 32 + q * 8]);
#pragma unroll
            for (int nhd = 0; nhd < 4; nhd++) {
                bf16x8 bv = *(const bf16x8*)(&sVt[(nhd * 16 + ln15) * SKP + c * 32 + q * 8]);
                accO[nhd] = __builtin_amdgcn_mfma_f32_16x16x32_bf16(ap, bv, accO[nhd], 0, 0, 0);
            }
        }
    }

    // final row-sum reduce across the 16-lane col group, then write O
    float inv[4];
#pragma unroll
    for (int r = 0; r < 4; r++) {
        float l = lrow[r];
#pragma unroll
        for (int off = 1; off < 16; off <<= 1)
            l += __shfl_xor(l, off);
        inv[r] = 1.0f / l;
    }
    ushort_t* ob = O + base;
#pragma unroll
    for (int nhd = 0; nhd < 4; nhd++)
#pragma unroll
        for (int r = 0; r < 4; r++)
            ob[(size_t)(q0 + w * 16 + q * 4 + r) * D_ + nhd * 16 + ln15] =
                f2bf(accO[nhd][r] * inv[r]);
}

// ---------------- fused residual-add + LayerNorm (fp32 + bf16 outputs) ----------------
__global__ __launch_bounds__(256) void ln_add_kernel(
    const float* __restrict__ a, const float* __restrict__ bres,
    const float* __restrict__ g, const float* __restrict__ be,
    float* __restrict__ of, ushort_t* __restrict__ ob)
{
    int row = blockIdx.x;
    int t = threadIdx.x;
    const float* ar = a + (size_t)row * D_;
    const float* br = bres + (size_t)row * D_;
    float x[4];
    float s = 0.f, sq = 0.f;
#pragma unroll
    for (int i = 0; i < 4; i++) {
        int c = t + i * 256;
        float v = ar[c] + br[c];
        x[i] = v; s += v; sq += v * v;
    }
#pragma unroll
    for (int off = 32; off; off >>= 1) {
        s += __shfl_xor(s, off);
        sq += __shfl_xor(sq, off);
    }
    __shared__ float rs[4], rq[4];
    int w = t >> 6;
    if ((t & 63) == 0) { rs[w] = s; rq[w] = sq; }
    __syncthreads();
    s = rs[0] + rs[1] + rs[2] + rs[3];
    sq = rq[0] + rq[1] + rq[2] + rq[3];
    float mu = s * (1.0f / D_);
    float var = sq * (1.0f / D_) - mu * mu;
    float rstd = rsqrtf(var + 1e-5f);
#pragma unroll
    for (int i = 0; i < 4; i++) {
        int c = t + i * 256;
        float y = (x[i] - mu) * rstd * g[c] + be[c];
        of[(size_t)row * D_ + c] = y;
        ob[(size_t)row * D_ + c] = f2bf(y);
    }
}

extern "C" void kernel_launch(void* const* d_in, const int* in_sizes, int n_in,
                              void* d_out, int out_size, void* d_ws, size_t ws_size,
                              hipStream_t stream) {
    const int*   x    = (const int*)d_in[0];
    const float* emb  = (const float*)d_in[1];
    const float* Wq   = (const float*)d_in[2];
    const float* Wk   = (const float*)d_in[3];
    const float* Wv   = (const float*)d_in[4];
    const float* Wo   = (const float*)d_in[5];
    const float* bo   = (const float*)d_in[6];
    const float* ln1g = (const float*)d_in[7];
    const float* ln1b = (const float*)d_in[8];
    const float* W1   = (const float*)d_in[9];
    const float* b1   = (const float*)d_in[10];
    const float* W2   = (const float*)d_in[11];
    const float* b2   = (const float*)d_in[12];
    const float* ln2g = (const float*)d_in[13];
    const float* ln2b = (const float*)d_in[14];

    char* ws = (char*)d_ws;
    float*    h   = (float*)(ws + 0);             // 16 MB fp32 residual
    ushort_t* hb  = (ushort_t*)(ws + 16777216);   // 8 MB bf16 h
    float*    t0  = (float*)(ws + 25165824);      // 16 MB fp32 gemm out
    float*    n1  = (float*)(ws + 41943040);      // 16 MB fp32 n1
    ushort_t* n1b = (ushort_t*)(ws + 58720256);   // 8 MB bf16 n1
    ushort_t* qb  = (ushort_t*)(ws + 67108864);   // 8 MB
    ushort_t* kb  = (ushort_t*)(ws + 75497472);   // 8 MB
    ushort_t* vb  = (ushort_t*)(ws + 83886080);   // 8 MB
    ushort_t* ab  = (ushort_t*)(ws + 92274688);   // 8 MB
    ushort_t* ff1 = (ushort_t*)(ws + 67108864);   // 32 MB, overlaps dead qkv/ab
    ushort_t* wqb = (ushort_t*)(ws + 100663296);  // 2 MB
    ushort_t* wkb = (ushort_t*)(ws + 102760448);  // 2 MB
    ushort_t* wvb = (ushort_t*)(ws + 104857600);  // 2 MB
    ushort_t* wob = (ushort_t*)(ws + 106954752);  // 2 MB
    ushort_t* w1b = (ushort_t*)(ws + 109051904);  // 8 MB
    ushort_t* w2b = (ushort_t*)(ws + 117440512);  // 8 MB  (total 120 MB)

    embed_kernel<<<NTOK, 256, 0, stream>>>(x, emb, h, hb);

    for (int l = 0; l < L_; l++) {
        const float* Wq_l = Wq + (size_t)l * D_ * D_;
        const float* Wk_l = Wk + (size_t)l * D_ * D_;
        const float* Wv_l = Wv + (size_t)l * D_ * D_;
        const float* Wo_l = Wo + (size_t)l * D_ * D_;
        const float* bo_l = bo + (size_t)l * D_;
        const float* W1_l = W1 + (size_t)l * D_ * 4 * D_;
        const float* b1_l = b1 + (size_t)l * 4 * D_;
        const float* W2_l = W2 + (size_t)l * 4 * D_ * D_;
        const float* b2_l = b2 + (size_t)l * D_;

        cvt_kernel<<<D_*D_/1024, 256, 0, stream>>>(Wq_l, wqb);
        cvt_kernel<<<D_*D_/1024, 256, 0, stream>>>(Wk_l, wkb);
        cvt_kernel<<<D_*D_/1024, 256, 0, stream>>>(Wv_l, wvb);
        cvt_kernel<<<D_*D_/1024, 256, 0, stream>>>(Wo_l, wob);
        cvt_kernel<<<4*D_*D_/1024, 256, 0, stream>>>(W1_l, w1b);
        cvt_kernel<<<4*D_*D_/1024, 256, 0, stream>>>(W2_l, w2b);

        dim3 gProj(D_ / 64, NTOK / 64);
        gemm_kernel<<<gProj, 256, 0, stream>>>(hb, wqb, nullptr, qb, NTOK, D_, D_, GEMM_OUT_BF16);
        gemm_kernel<<<gProj, 256, 0, stream>>>(hb, wkb, nullptr, kb, NTOK, D_, D_, GEMM_OUT_BF16);
        gemm_kernel<<<gProj, 256, 0, stream>>>(hb, wvb, nullptr, vb, NTOK, D_, D_, GEMM_OUT_BF16);

        attn_kernel<<<dim3(S_ / 64, H_, B_), 256, 0, stream>>>(qb, kb, vb, ab);

        gemm_kernel<<<gProj, 256, 0, stream>>>(ab, wob, bo_l, t0, NTOK, D_, D_, 0);
        ln_add_kernel<<<NTOK, 256, 0, stream>>>(t0, h, ln1g + l * D_, ln1b + l * D_, n1, n1b);

        dim3 gW1(4 * D_ / 64, NTOK / 64);
        gemm_kernel<<<gW1, 256, 0, stream>>>(n1b, w1b, b1_l, ff1, NTOK, 4 * D_, D_, GEMM_OUT_BF16 | GEMM_RELU);
        dim3 gW2(D_ / 64, NTOK / 64);
        gemm_kernel<<<gW2, 256, 0, stream>>>(ff1, w2b, b2_l, t0, NTOK, D_, 4 * D_, 0);

        float* of = (l == L_ - 1) ? (float*)d_out : h;
        ln_add_kernel<<<NTOK, 256, 0, stream>>>(t0, n1, ln2g + l * D_, ln2b + l * D_, of, hb);
    }
}